// Round 3
// baseline (182.276 us; speedup 1.0000x reference)
//
#include <hip/hip_runtime.h>

#define NB 1024

typedef __bf16 bf16x8 __attribute__((ext_vector_type(8)));
typedef float f32x4 __attribute__((ext_vector_type(4)));

union ABu { uint4 u; bf16x8 v; unsigned short s[8]; };

__device__ __forceinline__ unsigned short f2bf(float f) {
    unsigned int u = __builtin_bit_cast(unsigned int, f);
    u += 0x7fffu + ((u >> 16) & 1u);   // round-to-nearest-even
    return (unsigned short)(u >> 16);
}

// ---- prep 1: A[p][n] = x[p] @ W0[:64,:],  C[q][n] = y[q] @ W0[64:,:] + b0  (fp32) ----
__global__ void prep_ac(const float* __restrict__ x, const float* __restrict__ y,
                        const float* __restrict__ W0, const float* __restrict__ b0,
                        float* __restrict__ Aws, float* __restrict__ Cws) {
    __shared__ float row[64];
    int b = blockIdx.x;            // 0..1023 -> A rows, 1024..2047 -> C rows
    int t = threadIdx.x;           // 0..127  : output feature n
    bool isC = b >= 1024;
    int r = isC ? b - 1024 : b;
    const float* src = isC ? y : x;
    if (t < 64) row[t] = src[r * 64 + t];
    __syncthreads();
    const float* w = W0 + (isC ? 64 * 128 : 0);
    float acc = isC ? b0[t] : 0.f;
#pragma unroll
    for (int k = 0; k < 64; k++) acc += row[k] * w[k * 128 + t];
    (isC ? Cws : Aws)[r * 128 + t] = acc;
}

// ---- prep 2: transpose W1..W4 to bf16 [N][K] ----
// W1:(128,128) W2:(128,64) W3:(64,64) W4:(64,64)
__global__ void prep_w(const float* __restrict__ W1, const float* __restrict__ W2,
                       const float* __restrict__ W3, const float* __restrict__ W4,
                       unsigned short* __restrict__ W1t, unsigned short* __restrict__ W2t,
                       unsigned short* __restrict__ W3t, unsigned short* __restrict__ W4t) {
    int i = blockIdx.x * 256 + threadIdx.x;    // 32768 total
    if (i < 16384)      { int n = i >> 7, k = i & 127;               W1t[i] = f2bf(W1[k * 128 + n]); }
    else if (i < 24576) { int j = i - 16384; int n = j >> 7, k = j & 127; W2t[j] = f2bf(W2[k * 64 + n]); }
    else if (i < 28672) { int j = i - 24576; int n = j >> 6, k = j & 63;  W3t[j] = f2bf(W3[k * 64 + n]); }
    else                { int j = i - 28672; int n = j >> 6, k = j & 63;  W4t[j] = f2bf(W4[k * 64 + n]); }
}

#define MFMA(a, b, d) (d) = __builtin_amdgcn_mfma_f32_16x16x32_bf16((a), (b), (d), 0, 0, 0)

#define ZACC do { _Pragma("unroll") for (int i_ = 0; i_ < 4; i_++) \
                  _Pragma("unroll") for (int j_ = 0; j_ < 4; j_++) \
                      acc[i_][j_] = (f32x4){0.f, 0.f, 0.f, 0.f}; } while (0)

// relu(acc+bias) -> bf16 -> 64x64 LDS tile (128B rows, swizzle (row&7)<<4)
#define EPI64(DST, BPTR) do { \
    _Pragma("unroll") for (int nt = 0; nt < 4; nt++) { \
        float bias = (BPTR)[nt * 16 + c]; \
        _Pragma("unroll") for (int mt = 0; mt < 4; mt++) { \
            _Pragma("unroll") for (int r = 0; r < 4; r++) { \
                int row = mt * 16 + 4 * g + r; \
                int byo = (row << 7) + (((nt << 5) + (c << 1)) ^ ((row & 7) << 4)); \
                (DST)[byo >> 1] = f2bf(fmaxf(acc[mt][nt][r] + bias, 0.f)); \
            } \
        } \
    } \
} while (0)

// one K=64 MFMA layer reading a swizzled 64x64 LDS tile
#define LAYER64(SRC, WT) do { \
    _Pragma("unroll") for (int ks = 0; ks < 2; ks++) { \
        ABu Bf[4]; \
        _Pragma("unroll") for (int nt = 0; nt < 4; nt++) \
            Bf[nt].u = *(const uint4*)&(WT)[(nt * 16 + c) * 64 + ks * 32 + 8 * g]; \
        _Pragma("unroll") for (int mt = 0; mt < 4; mt++) { \
            int row = mt * 16 + c; \
            int byo = (row << 7) + ((((ks << 6) + (g << 4))) ^ ((row & 7) << 4)); \
            ABu av; av.u = *(const uint4*)&(SRC)[byo >> 1]; \
            _Pragma("unroll") for (int nt = 0; nt < 4; nt++) \
                MFMA(av.v, Bf[nt].v, acc[mt][nt]); \
        } \
    } \
} while (0)

__launch_bounds__(256, 2)
__global__ void critic_main(const float* __restrict__ Aws, const float* __restrict__ Cws,
                            const unsigned short* __restrict__ W1t, const unsigned short* __restrict__ W2t,
                            const unsigned short* __restrict__ W3t, const unsigned short* __restrict__ W4t,
                            const float* __restrict__ b1, const float* __restrict__ b2,
                            const float* __restrict__ b3, const float* __restrict__ b4,
                            const float* __restrict__ W5, const float* __restrict__ b5,
                            float* __restrict__ out) {
    __shared__ unsigned short hb[4][8192];   // 16KB per wave, private, no barriers
    int tid = threadIdx.x;
    int w = tid >> 6, lane = tid & 63;
    int g = lane >> 4, c = lane & 15;
    int pb = (blockIdx.x >> 6) * 16 + 4 * w;   // this wave's 4 p rows
    int qb = (blockIdx.x & 63) * 16;           // block's 16 q cols
    unsigned short* h1 = hb[w];                // [64][128] bf16, swizzle (row&15)<<4
    unsigned short* h2 = hb[w];                // [64][64], reuses bytes 0..8191 (wave LDS is in-order)
    unsigned short* h3 = hb[w] + 4096;         // [64][64], bytes 8192..16383

    // ---- h0 fragments: relu(A[p] + C[q]) built once, kept in registers ----
    ABu af[4][4];   // [ks][mt]
#pragma unroll
    for (int ks = 0; ks < 4; ks++) {
        const float* cp = &Cws[(qb + c) * 128 + ks * 32 + 8 * g];
        float4 c0 = *(const float4*)cp;
        float4 c1 = *(const float4*)(cp + 4);
#pragma unroll
        for (int mt = 0; mt < 4; mt++) {
            const float* ap = &Aws[(pb + mt) * 128 + ks * 32 + 8 * g];
            float4 a0 = *(const float4*)ap;
            float4 a1 = *(const float4*)(ap + 4);
            ABu av;
            av.s[0] = f2bf(fmaxf(a0.x + c0.x, 0.f));
            av.s[1] = f2bf(fmaxf(a0.y + c0.y, 0.f));
            av.s[2] = f2bf(fmaxf(a0.z + c0.z, 0.f));
            av.s[3] = f2bf(fmaxf(a0.w + c0.w, 0.f));
            av.s[4] = f2bf(fmaxf(a1.x + c1.x, 0.f));
            av.s[5] = f2bf(fmaxf(a1.y + c1.y, 0.f));
            av.s[6] = f2bf(fmaxf(a1.z + c1.z, 0.f));
            av.s[7] = f2bf(fmaxf(a1.w + c1.w, 0.f));
            af[ks][mt] = av;
        }
    }

    f32x4 acc[4][4];

    // ---- layer W1: K=128 -> N=128, two N-halves of 64 ----
#pragma unroll
    for (int half = 0; half < 2; half++) {
        ZACC;
#pragma unroll
        for (int ks = 0; ks < 4; ks++) {
            ABu Bf[4];
#pragma unroll
            for (int nt = 0; nt < 4; nt++)
                Bf[nt].u = *(const uint4*)&W1t[(half * 64 + nt * 16 + c) * 128 + ks * 32 + 8 * g];
#pragma unroll
            for (int mt = 0; mt < 4; mt++)
#pragma unroll
                for (int nt = 0; nt < 4; nt++)
                    MFMA(af[ks][mt].v, Bf[nt].v, acc[mt][nt]);
        }
        // epilogue -> h1 [64][128] (256B rows, swizzle (row&15)<<4)
#pragma unroll
        for (int nt = 0; nt < 4; nt++) {
            float bias = b1[half * 64 + nt * 16 + c];
#pragma unroll
            for (int mt = 0; mt < 4; mt++) {
#pragma unroll
                for (int r = 0; r < 4; r++) {
                    int row = mt * 16 + 4 * g + r;
                    int byo = (row << 8) + (((half << 7) + (nt << 5) + (c << 1)) ^ ((row & 15) << 4));
                    h1[byo >> 1] = f2bf(fmaxf(acc[mt][nt][r] + bias, 0.f));
                }
            }
        }
    }

    // ---- layer W2: K=128 -> N=64 ----
    ZACC;
#pragma unroll
    for (int ks = 0; ks < 4; ks++) {
        ABu Bf[4];
#pragma unroll
        for (int nt = 0; nt < 4; nt++)
            Bf[nt].u = *(const uint4*)&W2t[(nt * 16 + c) * 128 + ks * 32 + 8 * g];
#pragma unroll
        for (int mt = 0; mt < 4; mt++) {
            int row = mt * 16 + c;
            int byo = (row << 8) + ((((ks << 6) + (g << 4))) ^ ((row & 15) << 4));
            ABu av; av.u = *(const uint4*)&h1[byo >> 1];
#pragma unroll
            for (int nt = 0; nt < 4; nt++)
                MFMA(av.v, Bf[nt].v, acc[mt][nt]);
        }
    }
    EPI64(h2, b2);

    // ---- layer W3: K=64 -> N=64 ----
    ZACC;
    LAYER64(h2, W3t);
    EPI64(h3, b3);

    // ---- layer W4: K=64 -> N=64 ----
    ZACC;
    LAYER64(h3, W4t);

    // ---- final: h4 = relu(acc + b4); out = h4 @ W5 + b5  (fp32) ----
    float w5v[4], b4v[4];
#pragma unroll
    for (int nt = 0; nt < 4; nt++) { w5v[nt] = W5[nt * 16 + c]; b4v[nt] = b4[nt * 16 + c]; }
    float b5s = b5[0];
#pragma unroll
    for (int mt = 0; mt < 4; mt++) {
        float s0 = 0.f, s1 = 0.f, s2 = 0.f, s3 = 0.f;
#pragma unroll
        for (int nt = 0; nt < 4; nt++) {
            f32x4 v = acc[mt][nt];
            float wv = w5v[nt], bb = b4v[nt];
            s0 += fmaxf(v[0] + bb, 0.f) * wv;
            s1 += fmaxf(v[1] + bb, 0.f) * wv;
            s2 += fmaxf(v[2] + bb, 0.f) * wv;
            s3 += fmaxf(v[3] + bb, 0.f) * wv;
        }
#pragma unroll
        for (int m = 1; m <= 8; m <<= 1) {
            s0 += __shfl_xor(s0, m);
            s1 += __shfl_xor(s1, m);
            s2 += __shfl_xor(s2, m);
            s3 += __shfl_xor(s3, m);
        }
        if (c < 4) {
            float val = (c == 0) ? s0 : (c == 1) ? s1 : (c == 2) ? s2 : s3;
            out[(pb + mt) * NB + (qb + 4 * g + c)] = val + b5s;
        }
    }
}

extern "C" void kernel_launch(void* const* d_in, const int* in_sizes, int n_in,
                              void* d_out, int out_size, void* d_ws, size_t ws_size,
                              hipStream_t stream) {
    const float* x  = (const float*)d_in[0];
    const float* y  = (const float*)d_in[1];
    const float* W0 = (const float*)d_in[2];
    const float* b0 = (const float*)d_in[3];
    const float* W1 = (const float*)d_in[4];
    const float* b1 = (const float*)d_in[5];
    const float* W2 = (const float*)d_in[6];
    const float* b2 = (const float*)d_in[7];
    const float* W3 = (const float*)d_in[8];
    const float* b3 = (const float*)d_in[9];
    const float* W4 = (const float*)d_in[10];
    const float* b4 = (const float*)d_in[11];
    const float* W5 = (const float*)d_in[12];
    const float* b5 = (const float*)d_in[13];
    float* out = (float*)d_out;

    char* ws = (char*)d_ws;
    float* Aws = (float*)ws;                                    // 1024*128 f32 = 512KB
    float* Cws = (float*)(ws + 524288);                         // 512KB
    unsigned short* W1t = (unsigned short*)(ws + 1048576);      // 32KB (128x128)
    unsigned short* W2t = (unsigned short*)(ws + 1048576 + 32768);   // 16KB (64x128)
    unsigned short* W3t = (unsigned short*)(ws + 1048576 + 49152);   // 8KB  (64x64)
    unsigned short* W4t = (unsigned short*)(ws + 1048576 + 57344);   // 8KB  (64x64)

    prep_ac<<<2048, 128, 0, stream>>>(x, y, W0, b0, Aws, Cws);
    prep_w<<<128, 256, 0, stream>>>(W1, W2, W3, W4, W1t, W2t, W3t, W4t);
    critic_main<<<4096, 256, 0, stream>>>(Aws, Cws, W1t, W2t, W3t, W4t,
                                          b1, b2, b3, b4, W5, b5, out);
}